// Round 3
// baseline (1996.564 us; speedup 1.0000x reference)
//
#include <hip/hip_runtime.h>
#include <stdint.h>

#define B_ 8
#define S_ 4096
#define D_ 1024
#define H_ 16
#define K_ 256
#define DH_ 64

typedef unsigned short ushort_t;
typedef __attribute__((ext_vector_type(8))) short short8;
typedef __attribute__((ext_vector_type(4))) short short4x;
typedef __attribute__((ext_vector_type(4))) float floatx4;

static __device__ __forceinline__ float u2f(unsigned short u){
  union { float f; unsigned int i; } v; v.i = ((unsigned int)u) << 16; return v.f;
}
static __device__ __forceinline__ unsigned short f2u(float f){
  union { float f; unsigned int i; } v; v.f = f;
  unsigned int r = v.i + 0x7fffu + ((v.i >> 16) & 1u);   // RNE bf16
  return (unsigned short)(r >> 16);
}

// ---------------- K1: per-batch lengths (mask fp32) ----------------
__global__ __launch_bounds__(256) void k_len(const float* __restrict__ mask,
                                             int* __restrict__ len, float* __restrict__ invl){
  int b = blockIdx.x, t = threadIdx.x;
  __shared__ int cnt[256];
  int c = 0;
  for(int s = t; s < S_; s += 256) c += (mask[b*S_ + s] > -1.0f) ? 1 : 0;
  cnt[t] = c; __syncthreads();
  for(int o = 128; o > 0; o >>= 1){ if(t < o) cnt[t] += cnt[t+o]; __syncthreads(); }
  if(t == 0){ len[b] = cnt[0]; invl[b] = rsqrtf((float)cnt[0]); }
}

// ---------------- K2: spk/spv = inv_sqrt_len * masked column sums of proj (fp32) ----------------
__global__ __launch_bounds__(256) void k_sp(const float* __restrict__ pk, const float* __restrict__ pv,
                                            const int* __restrict__ len, const float* __restrict__ invl,
                                            float* __restrict__ spk, float* __restrict__ spv){
  int b = blockIdx.x, sel = blockIdx.y, k = threadIdx.x;
  const float* p = sel ? pv : pk;
  float* sp = sel ? spv : spk;
  int L = len[b];
  float acc = 0.f;
  for(int s = 0; s < L; s++) acc += p[s*K_ + k];
  sp[b*K_ + k] = acc * invl[b];
}

// ---------------- K2b: fp32 -> bf16 elementwise convert ----------------
__global__ __launch_bounds__(256) void k_cvt(const float* __restrict__ src, ushort_t* __restrict__ dst, int n4){
  int i = blockIdx.x * 256 + threadIdx.x;
  if(i >= n4) return;
  const float4 a = *(const float4*)(src + i*4);
  short4x v;
  v[0] = (short)f2u(a.x); v[1] = (short)f2u(a.y); v[2] = (short)f2u(a.z); v[3] = (short)f2u(a.w);
  *(short4x*)(dst + i*4) = v;
}

// ---------------- K3: 64x64-tile transpose fp32 -> bf16 ----------------
__global__ __launch_bounds__(256) void k_trcvt(const float* __restrict__ src, ushort_t* __restrict__ dst,
                                               int R, int C, long sstride, long dstride){
  __shared__ __align__(16) short t[64*66];
  const float* s0 = src + (size_t)blockIdx.z * sstride;
  ushort_t* d0 = dst + (size_t)blockIdx.z * dstride;
  int r0 = blockIdx.y * 64, c0 = blockIdx.x * 64;
  int tid = threadIdx.x;
#pragma unroll
  for(int i = 0; i < 2; i++){
    int f = tid + 256*i;
    int r = f >> 3, c = (f & 7) * 8;
    const float* p = s0 + (size_t)(r0 + r) * C + (c0 + c);
    float4 a = *(const float4*)p;
    float4 b2 = *(const float4*)(p + 4);
    short* q = &t[r*66 + c];
    q[0]=(short)f2u(a.x); q[1]=(short)f2u(a.y); q[2]=(short)f2u(a.z); q[3]=(short)f2u(a.w);
    q[4]=(short)f2u(b2.x); q[5]=(short)f2u(b2.y); q[6]=(short)f2u(b2.z); q[7]=(short)f2u(b2.w);
  }
  __syncthreads();
#pragma unroll
  for(int i = 0; i < 2; i++){
    int f = tid + 256*i;
    int dc = f >> 3, sg = f & 7;
    short8 v;
#pragma unroll
    for(int j = 0; j < 8; j++) v[j] = t[(sg*8 + j)*66 + dc];
    *(short8*)(d0 + (size_t)(c0 + dc) * R + (r0 + sg*8)) = v;
  }
}

// ---------------- K4: Xp[b,m,d] = invl * sum_{s<L} pT[m,s]*XT[b,d,s]  (bf16 in, bf16 out) ----------------
__global__ __launch_bounds__(256) void k_xp(const ushort_t* __restrict__ pkT, const ushort_t* __restrict__ pvT,
      const ushort_t* __restrict__ XT, const int* __restrict__ len, const float* __restrict__ invl,
      ushort_t* __restrict__ XpK, ushort_t* __restrict__ XpV){
  int b = blockIdx.y, sel = blockIdx.z;
  const ushort_t* A = sel ? pvT : pkT;               // (256, 4096)
  ushort_t* hi = sel ? XpV : XpK;
  int m0 = (blockIdx.x & 1) * 128;
  int n0 = (blockIdx.x >> 1) * 128;
  const ushort_t* Bm = XT + (size_t)b * D_ * S_;     // (1024, 4096)
  int L = len[b];
  int nk = (L + 31) >> 5;
  bool tail = (L & 31) != 0;
  __shared__ __align__(16) short As[128*32];
  __shared__ __align__(16) short Bs[128*32];
  int tid = threadIdx.x, lane = tid & 63, w = tid >> 6;
  int mW = (w & 1) * 64, nW = (w >> 1) * 64;
  int lm = lane & 15, lk = (lane >> 4) * 8;
  floatx4 acc[4][4];
#pragma unroll
  for(int i = 0; i < 4; i++)
#pragma unroll
    for(int j = 0; j < 4; j++) acc[i][j] = (floatx4)0.f;
  for(int ks = 0; ks < nk; ks++){
    int k0 = ks << 5;
    short8 va[2], vb[2];
#pragma unroll
    for(int i = 0; i < 2; i++){
      int f = i*256 + tid;
      int row = f >> 2, col = (f & 3) * 8;
      va[i] = *(const short8*)(A  + (size_t)(m0+row)*S_ + (k0+col));
      vb[i] = *(const short8*)(Bm + (size_t)(n0+row)*S_ + (k0+col));
    }
    if(tail && ks == nk-1){
      int rlim = L - k0;                             // 1..31
#pragma unroll
      for(int i = 0; i < 2; i++){
        int col = ((i*256 + tid) & 3) * 8;
#pragma unroll
        for(int j = 0; j < 8; j++) if(col + j >= rlim) va[i][j] = 0;
      }
    }
    __syncthreads();
#pragma unroll
    for(int i = 0; i < 2; i++){
      int f = i*256 + tid;
      *(short8*)&As[f*8] = va[i];
      *(short8*)&Bs[f*8] = vb[i];
    }
    __syncthreads();
    short8 af[4], bfr[4];
#pragma unroll
    for(int i = 0; i < 4; i++) af[i]  = *(const short8*)&As[(mW + 16*i + lm)*32 + lk];
#pragma unroll
    for(int j = 0; j < 4; j++) bfr[j] = *(const short8*)&Bs[(nW + 16*j + lm)*32 + lk];
#pragma unroll
    for(int i = 0; i < 4; i++)
#pragma unroll
      for(int j = 0; j < 4; j++)
        acc[i][j] = __builtin_amdgcn_mfma_f32_16x16x32_bf16(af[i], bfr[j], acc[i][j], 0, 0, 0);
  }
  float sc = invl[b];
#pragma unroll
  for(int i = 0; i < 4; i++){
#pragma unroll
    for(int j = 0; j < 4; j++){
      int col = n0 + nW + 16*j + lm;
#pragma unroll
      for(int r = 0; r < 4; r++){
        int row = m0 + mW + 16*i + (lane>>4)*4 + r;
        hi[((size_t)b*K_ + row)*D_ + col] = f2u(acc[i][j][r] * sc);
      }
    }
  }
}

// ---------------- K5: k/v = Xp @ W^T + sp*bias; k:(B,H,K,DH) bf16, v:(B,H,DH,K) bf16 ----------------
__global__ __launch_bounds__(256) void k_kv(const ushort_t* __restrict__ XpK, const ushort_t* __restrict__ XpV,
      const ushort_t* __restrict__ Wk, const ushort_t* __restrict__ Wv,
      const float* __restrict__ bk, const float* __restrict__ bv,
      const float* __restrict__ spk, const float* __restrict__ spv,
      ushort_t* __restrict__ kten, ushort_t* __restrict__ vTt){
  int b = blockIdx.y, sel = blockIdx.z;
  const ushort_t* Ab = (sel ? XpV : XpK) + (size_t)b*K_*D_;
  const ushort_t* W = sel ? Wv : Wk;
  const float* bias = sel ? bv : bk;
  const float* sp = (sel ? spv : spk) + b*K_;
  int m0 = (blockIdx.x & 1) * 128;
  int n0 = (blockIdx.x >> 1) * 128;
  __shared__ __align__(16) short As[128*32];
  __shared__ __align__(16) short Bs[128*32];
  int tid = threadIdx.x, lane = tid & 63, w = tid >> 6;
  int mW = (w & 1) * 64, nW = (w >> 1) * 64;
  int lm = lane & 15, lk = (lane >> 4) * 8;
  floatx4 acc[4][4];
#pragma unroll
  for(int i = 0; i < 4; i++)
#pragma unroll
    for(int j = 0; j < 4; j++) acc[i][j] = (floatx4)0.f;
  for(int ks = 0; ks < 32; ks++){
    int k0 = ks << 5;
    short8 va[2], vb[2];
#pragma unroll
    for(int i = 0; i < 2; i++){
      int f = i*256 + tid;
      int row = f >> 2, col = (f & 3) * 8;
      va[i] = *(const short8*)(Ab + (size_t)(m0+row)*D_ + (k0+col));
      vb[i] = *(const short8*)(W  + (size_t)(n0+row)*D_ + (k0+col));
    }
    __syncthreads();
#pragma unroll
    for(int i = 0; i < 2; i++){
      int f = i*256 + tid;
      *(short8*)&As[f*8] = va[i];
      *(short8*)&Bs[f*8] = vb[i];
    }
    __syncthreads();
    short8 af[4], bfr[4];
#pragma unroll
    for(int i = 0; i < 4; i++) af[i]  = *(const short8*)&As[(mW + 16*i + lm)*32 + lk];
#pragma unroll
    for(int j = 0; j < 4; j++) bfr[j] = *(const short8*)&Bs[(nW + 16*j + lm)*32 + lk];
#pragma unroll
    for(int i = 0; i < 4; i++)
#pragma unroll
      for(int j = 0; j < 4; j++)
        acc[i][j] = __builtin_amdgcn_mfma_f32_16x16x32_bf16(af[i], bfr[j], acc[i][j], 0, 0, 0);
  }
#pragma unroll
  for(int j = 0; j < 4; j++){
    int col = n0 + nW + 16*j + lm;
    float bb = bias[col];
    int hcol = col >> 6, dcol = col & 63;
#pragma unroll
    for(int i = 0; i < 4; i++){
#pragma unroll
      for(int r = 0; r < 4; r++){
        int row = m0 + mW + 16*i + (lane>>4)*4 + r;
        float val = acc[i][j][r] + sp[row]*bb;
        if(sel == 0) kten[(((size_t)b*H_ + hcol)*K_ + row)*DH_ + dcol] = f2u(val);
        else         vTt [(((size_t)b*H_ + hcol)*DH_ + dcol)*K_ + row] = f2u(val);
      }
    }
  }
}

// ---------------- K6: q = X @ Wq^T + bq  -> d_out (B,S,D) fp32 ----------------
__global__ __launch_bounds__(256) void k_q(const float* __restrict__ X, const ushort_t* __restrict__ Wq,
                                           const float* __restrict__ bq, float* __restrict__ out){
  int m0 = (int)(blockIdx.x >> 3) * 128;
  int n0 = (int)(blockIdx.x & 7) * 128;
  __shared__ __align__(16) short As[128*32];
  __shared__ __align__(16) short Bs[128*32];
  int tid = threadIdx.x, lane = tid & 63, w = tid >> 6;
  int mW = (w & 1) * 64, nW = (w >> 1) * 64;
  int lm = lane & 15, lk = (lane >> 4) * 8;
  floatx4 acc[4][4];
#pragma unroll
  for(int i = 0; i < 4; i++)
#pragma unroll
    for(int j = 0; j < 4; j++) acc[i][j] = (floatx4)0.f;
  for(int ks = 0; ks < 32; ks++){
    int k0 = ks << 5;
    short8 va[2], vb[2];
#pragma unroll
    for(int i = 0; i < 2; i++){
      int f = i*256 + tid;
      int row = f >> 2, col = (f & 3) * 8;
      const float* p = X + (size_t)(m0+row)*D_ + (k0+col);
      float4 a = *(const float4*)p;
      float4 b2 = *(const float4*)(p + 4);
      short8 v;
      v[0]=(short)f2u(a.x); v[1]=(short)f2u(a.y); v[2]=(short)f2u(a.z); v[3]=(short)f2u(a.w);
      v[4]=(short)f2u(b2.x); v[5]=(short)f2u(b2.y); v[6]=(short)f2u(b2.z); v[7]=(short)f2u(b2.w);
      va[i] = v;
      vb[i] = *(const short8*)(Wq + (size_t)(n0+row)*D_ + (k0+col));
    }
    __syncthreads();
#pragma unroll
    for(int i = 0; i < 2; i++){
      int f = i*256 + tid;
      *(short8*)&As[f*8] = va[i];
      *(short8*)&Bs[f*8] = vb[i];
    }
    __syncthreads();
    short8 af[4], bfr[4];
#pragma unroll
    for(int i = 0; i < 4; i++) af[i]  = *(const short8*)&As[(mW + 16*i + lm)*32 + lk];
#pragma unroll
    for(int j = 0; j < 4; j++) bfr[j] = *(const short8*)&Bs[(nW + 16*j + lm)*32 + lk];
#pragma unroll
    for(int i = 0; i < 4; i++)
#pragma unroll
      for(int j = 0; j < 4; j++)
        acc[i][j] = __builtin_amdgcn_mfma_f32_16x16x32_bf16(af[i], bfr[j], acc[i][j], 0, 0, 0);
  }
#pragma unroll
  for(int j = 0; j < 4; j++){
    int col = n0 + nW + 16*j + lm;
    float bb = bq[col];
#pragma unroll
    for(int i = 0; i < 4; i++){
#pragma unroll
      for(int r = 0; r < 4; r++){
        int row = m0 + mW + 16*i + (lane>>4)*4 + r;
        out[(size_t)row*D_ + col] = acc[i][j][r] + bb;
      }
    }
  }
}

// ---------------- K7: attention; q read fp32 from d_out, ctx written fp32 to d_out ----------------
__global__ __launch_bounds__(256) void k_attn(float* __restrict__ out,
                                              const ushort_t* __restrict__ kten,
                                              const ushort_t* __restrict__ vTt){
  int x = blockIdx.x;
  int h = x & 15, b = (x >> 4) & 7, st = x >> 7;
  int s0 = st * 64;
  __shared__ __align__(16) short q_s[8*64*8];      // q: [kb<8][row<64][8]   (k-hat = dh)
  __shared__ __align__(16) short kp_s[8*256*8];    // k: [kb<8][row<256][8]; reused for P
  __shared__ __align__(16) short v_s[32*64*8];     // vT: [kb<32][row<64][8] (k-hat = key idx)
  int tid = threadIdx.x, lane = tid & 63, w = tid >> 6;
  int lm = lane & 15, lq = lane >> 4;
  const ushort_t* kb_g = kten + ((size_t)b*H_ + h)*K_*DH_;
  const ushort_t* vb_g = vTt + ((size_t)b*H_ + h)*DH_*K_;
  const float* qb_g = out + ((size_t)b*S_ + s0)*D_ + h*DH_;
  short8 vq[2], vk[8], vv[8];
#pragma unroll
  for(int i = 0; i < 2; i++){                       // q: 64x64 fp32 -> bf16
    int f = i*256 + tid;
    const float* p = qb_g + (size_t)(f & 63)*D_ + (f >> 6)*8;
    float4 a = *(const float4*)p;
    float4 b2 = *(const float4*)(p + 4);
    short8 v;
    v[0]=(short)f2u(a.x); v[1]=(short)f2u(a.y); v[2]=(short)f2u(a.z); v[3]=(short)f2u(a.w);
    v[4]=(short)f2u(b2.x); v[5]=(short)f2u(b2.y); v[6]=(short)f2u(b2.z); v[7]=(short)f2u(b2.w);
    vq[i] = v;
  }
#pragma unroll
  for(int i = 0; i < 8; i++){                       // k: 256x64
    int f = i*256 + tid;
    vk[i] = *(const short8*)(kb_g + (f & 255)*DH_ + (f >> 8)*8);
  }
#pragma unroll
  for(int i = 0; i < 8; i++){                       // vT: 64x256
    int f = i*256 + tid;
    vv[i] = *(const short8*)(vb_g + (f & 63)*K_ + (f >> 6)*8);
  }
#pragma unroll
  for(int i = 0; i < 2; i++) *(short8*)&q_s[(i*256 + tid)*8] = vq[i];
#pragma unroll
  for(int i = 0; i < 8; i++) *(short8*)&kp_s[(i*256 + tid)*8] = vk[i];
#pragma unroll
  for(int i = 0; i < 8; i++) *(short8*)&v_s[(i*256 + tid)*8] = vv[i];
  __syncthreads();

  int rw = w * 16;                                   // this wave's q rows
  floatx4 accS[16];
#pragma unroll
  for(int n = 0; n < 16; n++) accS[n] = (floatx4)0.f;
#pragma unroll
  for(int ks = 0; ks < 2; ks++){
    int kb = ks*4 + lq;
    short8 a = *(const short8*)&q_s[(kb*64 + rw + lm)*8];
#pragma unroll
    for(int n = 0; n < 16; n++){
      short8 bf_ = *(const short8*)&kp_s[(kb*256 + 16*n + lm)*8];
      accS[n] = __builtin_amdgcn_mfma_f32_16x16x32_bf16(a, bf_, accS[n], 0, 0, 0);
    }
  }
  const float scl = 0.125f;                          // 1/sqrt(64)
  float invr[4];
#pragma unroll
  for(int r = 0; r < 4; r++){
    float mx = -1e30f;
#pragma unroll
    for(int n = 0; n < 16; n++) mx = fmaxf(mx, accS[n][r]);
    mx = fmaxf(mx, __shfl_xor(mx, 1));
    mx = fmaxf(mx, __shfl_xor(mx, 2));
    mx = fmaxf(mx, __shfl_xor(mx, 4));
    mx = fmaxf(mx, __shfl_xor(mx, 8));
    float sum = 0.f;
#pragma unroll
    for(int n = 0; n < 16; n++){
      float p = __expf((accS[n][r] - mx) * scl);
      accS[n][r] = p;
      sum += p;
    }
    sum += __shfl_xor(sum, 1);
    sum += __shfl_xor(sum, 2);
    sum += __shfl_xor(sum, 4);
    sum += __shfl_xor(sum, 8);
    invr[r] = 1.f / sum;
  }
  __syncthreads();                                    // everyone done reading kp_s as K
  short* p_s = &kp_s[w * 4096];                       // per-wave P: [kb<32][row<16][8]
#pragma unroll
  for(int n = 0; n < 16; n++){
    int kb2 = 2*n + (lm >> 3);
    int e = lane & 7;
#pragma unroll
    for(int r = 0; r < 4; r++){
      int row = lq*4 + r;
      p_s[(kb2*16 + row)*8 + e] = (short)f2u(accS[n][r]);
    }
  }
  floatx4 accC[4];
#pragma unroll
  for(int n = 0; n < 4; n++) accC[n] = (floatx4)0.f;
#pragma unroll
  for(int ks = 0; ks < 8; ks++){
    int kb = ks*4 + lq;
    short8 a = *(const short8*)&p_s[(kb*16 + lm)*8];
#pragma unroll
    for(int n = 0; n < 4; n++){
      short8 bf_ = *(const short8*)&v_s[(kb*64 + 16*n + lm)*8];
      accC[n] = __builtin_amdgcn_mfma_f32_16x16x32_bf16(a, bf_, accC[n], 0, 0, 0);
    }
  }
#pragma unroll
  for(int n = 0; n < 4; n++){
#pragma unroll
    for(int r = 0; r < 4; r++){
      int srow = s0 + rw + lq*4 + r;
      out[((size_t)b*S_ + srow)*D_ + h*DH_ + 16*n + lm] = accC[n][r] * invr[r];
    }
  }
}

extern "C" void kernel_launch(void* const* d_in, const int* in_sizes, int n_in,
                              void* d_out, int out_size, void* d_ws, size_t ws_size,
                              hipStream_t stream) {
  (void)in_sizes; (void)n_in; (void)out_size; (void)ws_size;
  const float* X    = (const float*)d_in[0];
  const float* mask = (const float*)d_in[1];
  const float* Wq   = (const float*)d_in[2];
  const float* bq   = (const float*)d_in[3];
  const float* Wk   = (const float*)d_in[4];
  const float* bk   = (const float*)d_in[5];
  const float* Wv   = (const float*)d_in[6];
  const float* bv   = (const float*)d_in[7];
  const float* pk   = (const float*)d_in[8];
  const float* pv   = (const float*)d_in[9];
  float* out = (float*)d_out;

  char* wsp = (char*)d_ws;
  int*   len  = (int*)wsp;
  float* invl = (float*)(wsp + 64);
  float* spk  = (float*)(wsp + 256);
  float* spv  = (float*)(wsp + 256 + 8192);
  ushort_t* pkT  = (ushort_t*)(wsp + 32768);          // 256x4096 bf16, 2 MB
  ushort_t* pvT  = pkT  + (size_t)K_*S_;
  ushort_t* Wqb  = pvT  + (size_t)K_*S_;              // 1024x1024 bf16, 2 MB each
  ushort_t* Wkb  = Wqb  + (size_t)D_*D_;
  ushort_t* Wvb  = Wkb  + (size_t)D_*D_;
  ushort_t* XpK  = Wvb  + (size_t)D_*D_;              // 8x256x1024 bf16, 4 MB each
  ushort_t* XpV  = XpK  + (size_t)B_*K_*D_;
  ushort_t* kten = XpV  + (size_t)B_*K_*D_;
  ushort_t* vTt  = kten + (size_t)B_*K_*D_;

  hipLaunchKernelGGL(k_len, dim3(8), dim3(256), 0, stream, mask, len, invl);
  hipLaunchKernelGGL(k_sp,  dim3(8,2), dim3(256), 0, stream, pk, pv, len, invl, spk, spv);
  hipLaunchKernelGGL(k_cvt, dim3(1024), dim3(256), 0, stream, Wq, Wqb, D_*D_/4);
  hipLaunchKernelGGL(k_cvt, dim3(1024), dim3(256), 0, stream, Wk, Wkb, D_*D_/4);
  hipLaunchKernelGGL(k_cvt, dim3(1024), dim3(256), 0, stream, Wv, Wvb, D_*D_/4);
  hipLaunchKernelGGL(k_trcvt, dim3(4,64,1), dim3(256), 0, stream, pk, pkT, S_, K_, 0L, 0L);
  hipLaunchKernelGGL(k_trcvt, dim3(4,64,1), dim3(256), 0, stream, pv, pvT, S_, K_, 0L, 0L);
  // X -> XT bf16 staged in d_out (dead until k_q overwrites it); fits: 67 MB in 134 MB
  hipLaunchKernelGGL(k_trcvt, dim3(16,64,8), dim3(256), 0, stream, X, (ushort_t*)out, S_, D_, (long)S_*D_, (long)D_*S_);
  hipLaunchKernelGGL(k_xp,  dim3(16,8,2), dim3(256), 0, stream, pkT, pvT, (const ushort_t*)out, len, invl, XpK, XpV);
  hipLaunchKernelGGL(k_kv,  dim3(16,8,2), dim3(256), 0, stream, XpK, XpV, Wkb, Wvb, bk, bv, spk, spv, kten, vTt);
  hipLaunchKernelGGL(k_q,   dim3(2048), dim3(256), 0, stream, X, Wqb, bq, out);
  hipLaunchKernelGGL(k_attn, dim3(8192), dim3(256), 0, stream, out, kten, vTt);
}

// Round 4
// 705.924 us; speedup vs baseline: 2.8283x; 2.8283x over previous
//
#include <hip/hip_runtime.h>
#include <stdint.h>

#define B_ 8
#define S_ 4096
#define D_ 1024
#define H_ 16
#define K_ 256
#define DH_ 64

typedef unsigned short ushort_t;
typedef __attribute__((ext_vector_type(8))) short short8;
typedef __attribute__((ext_vector_type(4))) short short4x;
typedef __attribute__((ext_vector_type(4))) float floatx4;

static __device__ __forceinline__ float u2f(unsigned short u){
  union { float f; unsigned int i; } v; v.i = ((unsigned int)u) << 16; return v.f;
}
static __device__ __forceinline__ unsigned short f2u(float f){
  union { float f; unsigned int i; } v; v.f = f;
  unsigned int r = v.i + 0x7fffu + ((v.i >> 16) & 1u);   // RNE bf16
  return (unsigned short)(r >> 16);
}

// ---------------- K1: per-batch lengths (mask fp32) ----------------
__global__ __launch_bounds__(256) void k_len(const float* __restrict__ mask,
                                             int* __restrict__ len, float* __restrict__ invl){
  int b = blockIdx.x, t = threadIdx.x;
  __shared__ int cnt[256];
  int c = 0;
  for(int s = t; s < S_; s += 256) c += (mask[b*S_ + s] > -1.0f) ? 1 : 0;
  cnt[t] = c; __syncthreads();
  for(int o = 128; o > 0; o >>= 1){ if(t < o) cnt[t] += cnt[t+o]; __syncthreads(); }
  if(t == 0){ len[b] = cnt[0]; invl[b] = rsqrtf((float)cnt[0]); }
}

// ---------------- K2a: partial masked column sums of proj over 128-row chunks ----------------
__global__ __launch_bounds__(256) void k_sp_part(const float* __restrict__ pk, const float* __restrict__ pv,
                                                 const float* __restrict__ mask, float* __restrict__ part){
  int c = blockIdx.x;            // 0..31 chunk
  int b = blockIdx.y;            // 0..7
  int sel = blockIdx.z;          // 0..1
  const float* p = sel ? pv : pk;
  int k = threadIdx.x;
  int s0 = c * 128;
  float acc = 0.f;
  for(int i = 0; i < 128; i++){
    int s = s0 + i;
    float mm = mask[b*S_ + s];                 // wave-uniform broadcast
    if(mm > -1.0f) acc += p[(size_t)s*K_ + k]; // coalesced 1KB per iter
  }
  part[(((size_t)(b*2 + sel))*32 + c)*K_ + k] = acc;
}

// ---------------- K2b: reduce partials, scale by invl ----------------
__global__ __launch_bounds__(256) void k_sp_red(const float* __restrict__ part, const float* __restrict__ invl,
                                                float* __restrict__ spk, float* __restrict__ spv){
  int b = blockIdx.x, sel = blockIdx.y, k = threadIdx.x;
  float acc = 0.f;
#pragma unroll
  for(int c = 0; c < 32; c++) acc += part[(((size_t)(b*2 + sel))*32 + c)*K_ + k];
  float r = acc * invl[b];
  if(sel) spv[b*K_ + k] = r; else spk[b*K_ + k] = r;
}

// ---------------- K2c: fp32 -> bf16 elementwise convert ----------------
__global__ __launch_bounds__(256) void k_cvt(const float* __restrict__ src, ushort_t* __restrict__ dst, int n4){
  int i = blockIdx.x * 256 + threadIdx.x;
  if(i >= n4) return;
  const float4 a = *(const float4*)(src + i*4);
  short4x v;
  v[0] = (short)f2u(a.x); v[1] = (short)f2u(a.y); v[2] = (short)f2u(a.z); v[3] = (short)f2u(a.w);
  *(short4x*)(dst + i*4) = v;
}

// ---------------- K3: 64x64-tile transpose fp32 -> bf16 ----------------
__global__ __launch_bounds__(256) void k_trcvt(const float* __restrict__ src, ushort_t* __restrict__ dst,
                                               int R, int C, long sstride, long dstride){
  __shared__ __align__(16) short t[64*66];
  const float* s0 = src + (size_t)blockIdx.z * sstride;
  ushort_t* d0 = dst + (size_t)blockIdx.z * dstride;
  int r0 = blockIdx.y * 64, c0 = blockIdx.x * 64;
  int tid = threadIdx.x;
#pragma unroll
  for(int i = 0; i < 2; i++){
    int f = tid + 256*i;
    int r = f >> 3, c = (f & 7) * 8;
    const float* p = s0 + (size_t)(r0 + r) * C + (c0 + c);
    float4 a = *(const float4*)p;
    float4 b2 = *(const float4*)(p + 4);
    short* q = &t[r*66 + c];
    q[0]=(short)f2u(a.x); q[1]=(short)f2u(a.y); q[2]=(short)f2u(a.z); q[3]=(short)f2u(a.w);
    q[4]=(short)f2u(b2.x); q[5]=(short)f2u(b2.y); q[6]=(short)f2u(b2.z); q[7]=(short)f2u(b2.w);
  }
  __syncthreads();
#pragma unroll
  for(int i = 0; i < 2; i++){
    int f = tid + 256*i;
    int dc = f >> 3, sg = f & 7;
    short8 v;
#pragma unroll
    for(int j = 0; j < 8; j++) v[j] = t[(sg*8 + j)*66 + dc];
    *(short8*)(d0 + (size_t)(c0 + dc) * R + (r0 + sg*8)) = v;
  }
}

// ---------------- K4: Xp[b,m,d] = invl * sum_{s<L} pT[m,s]*XT[b,d,s]  (bf16 in, bf16 out) ----------------
__global__ __launch_bounds__(256) void k_xp(const ushort_t* __restrict__ pkT, const ushort_t* __restrict__ pvT,
      const ushort_t* __restrict__ XT, const int* __restrict__ len, const float* __restrict__ invl,
      ushort_t* __restrict__ XpK, ushort_t* __restrict__ XpV){
  int b = blockIdx.y, sel = blockIdx.z;
  const ushort_t* A = sel ? pvT : pkT;               // (256, 4096)
  ushort_t* hi = sel ? XpV : XpK;
  int m0 = (blockIdx.x & 1) * 128;
  int n0 = (blockIdx.x >> 1) * 128;
  const ushort_t* Bm = XT + (size_t)b * D_ * S_;     // (1024, 4096)
  int L = len[b];
  int nk = (L + 31) >> 5;
  bool tail = (L & 31) != 0;
  __shared__ __align__(16) short As[128*32];
  __shared__ __align__(16) short Bs[128*32];
  int tid = threadIdx.x, lane = tid & 63, w = tid >> 6;
  int mW = (w & 1) * 64, nW = (w >> 1) * 64;
  int lm = lane & 15, lk = (lane >> 4) * 8;
  floatx4 acc[4][4];
#pragma unroll
  for(int i = 0; i < 4; i++)
#pragma unroll
    for(int j = 0; j < 4; j++) acc[i][j] = (floatx4)0.f;
  for(int ks = 0; ks < nk; ks++){
    int k0 = ks << 5;
    short8 va[2], vb[2];
#pragma unroll
    for(int i = 0; i < 2; i++){
      int f = i*256 + tid;
      int row = f >> 2, col = (f & 3) * 8;
      va[i] = *(const short8*)(A  + (size_t)(m0+row)*S_ + (k0+col));
      vb[i] = *(const short8*)(Bm + (size_t)(n0+row)*S_ + (k0+col));
    }
    if(tail && ks == nk-1){
      int rlim = L - k0;                             // 1..31
#pragma unroll
      for(int i = 0; i < 2; i++){
        int col = ((i*256 + tid) & 3) * 8;
#pragma unroll
        for(int j = 0; j < 8; j++) if(col + j >= rlim) va[i][j] = 0;
      }
    }
    __syncthreads();
#pragma unroll
    for(int i = 0; i < 2; i++){
      int f = i*256 + tid;
      *(short8*)&As[f*8] = va[i];
      *(short8*)&Bs[f*8] = vb[i];
    }
    __syncthreads();
    short8 af[4], bfr[4];
#pragma unroll
    for(int i = 0; i < 4; i++) af[i]  = *(const short8*)&As[(mW + 16*i + lm)*32 + lk];
#pragma unroll
    for(int j = 0; j < 4; j++) bfr[j] = *(const short8*)&Bs[(nW + 16*j + lm)*32 + lk];
#pragma unroll
    for(int i = 0; i < 4; i++)
#pragma unroll
      for(int j = 0; j < 4; j++)
        acc[i][j] = __builtin_amdgcn_mfma_f32_16x16x32_bf16(af[i], bfr[j], acc[i][j], 0, 0, 0);
  }
  float sc = invl[b];
#pragma unroll
  for(int i = 0; i < 4; i++){
#pragma unroll
    for(int j = 0; j < 4; j++){
      int col = n0 + nW + 16*j + lm;
#pragma unroll
      for(int r = 0; r < 4; r++){
        int row = m0 + mW + 16*i + (lane>>4)*4 + r;
        hi[((size_t)b*K_ + row)*D_ + col] = f2u(acc[i][j][r] * sc);
      }
    }
  }
}

// ---------------- K5: k/v = Xp @ W^T + sp*bias; k:(B,H,K,DH) bf16, v:(B,H,DH,K) bf16 ----------------
__global__ __launch_bounds__(256) void k_kv(const ushort_t* __restrict__ XpK, const ushort_t* __restrict__ XpV,
      const ushort_t* __restrict__ Wk, const ushort_t* __restrict__ Wv,
      const float* __restrict__ bk, const float* __restrict__ bv,
      const float* __restrict__ spk, const float* __restrict__ spv,
      ushort_t* __restrict__ kten, ushort_t* __restrict__ vTt){
  int b = blockIdx.y, sel = blockIdx.z;
  const ushort_t* Ab = (sel ? XpV : XpK) + (size_t)b*K_*D_;
  const ushort_t* W = sel ? Wv : Wk;
  const float* bias = sel ? bv : bk;
  const float* sp = (sel ? spv : spk) + b*K_;
  int m0 = (blockIdx.x & 1) * 128;
  int n0 = (blockIdx.x >> 1) * 128;
  __shared__ __align__(16) short As[128*32];
  __shared__ __align__(16) short Bs[128*32];
  int tid = threadIdx.x, lane = tid & 63, w = tid >> 6;
  int mW = (w & 1) * 64, nW = (w >> 1) * 64;
  int lm = lane & 15, lk = (lane >> 4) * 8;
  floatx4 acc[4][4];
#pragma unroll
  for(int i = 0; i < 4; i++)
#pragma unroll
    for(int j = 0; j < 4; j++) acc[i][j] = (floatx4)0.f;
  for(int ks = 0; ks < 32; ks++){
    int k0 = ks << 5;
    short8 va[2], vb[2];
#pragma unroll
    for(int i = 0; i < 2; i++){
      int f = i*256 + tid;
      int row = f >> 2, col = (f & 3) * 8;
      va[i] = *(const short8*)(Ab + (size_t)(m0+row)*D_ + (k0+col));
      vb[i] = *(const short8*)(W  + (size_t)(n0+row)*D_ + (k0+col));
    }
    __syncthreads();
#pragma unroll
    for(int i = 0; i < 2; i++){
      int f = i*256 + tid;
      *(short8*)&As[f*8] = va[i];
      *(short8*)&Bs[f*8] = vb[i];
    }
    __syncthreads();
    short8 af[4], bfr[4];
#pragma unroll
    for(int i = 0; i < 4; i++) af[i]  = *(const short8*)&As[(mW + 16*i + lm)*32 + lk];
#pragma unroll
    for(int j = 0; j < 4; j++) bfr[j] = *(const short8*)&Bs[(nW + 16*j + lm)*32 + lk];
#pragma unroll
    for(int i = 0; i < 4; i++)
#pragma unroll
      for(int j = 0; j < 4; j++)
        acc[i][j] = __builtin_amdgcn_mfma_f32_16x16x32_bf16(af[i], bfr[j], acc[i][j], 0, 0, 0);
  }
#pragma unroll
  for(int j = 0; j < 4; j++){
    int col = n0 + nW + 16*j + lm;
    float bb = bias[col];
    int hcol = col >> 6, dcol = col & 63;
#pragma unroll
    for(int i = 0; i < 4; i++){
#pragma unroll
      for(int r = 0; r < 4; r++){
        int row = m0 + mW + 16*i + (lane>>4)*4 + r;
        float val = acc[i][j][r] + sp[row]*bb;
        if(sel == 0) kten[(((size_t)b*H_ + hcol)*K_ + row)*DH_ + dcol] = f2u(val);
        else         vTt [(((size_t)b*H_ + hcol)*DH_ + dcol)*K_ + row] = f2u(val);
      }
    }
  }
}

// ---------------- K6: q = X @ Wq^T + bq  -> d_out (B,S,D) fp32 ----------------
__global__ __launch_bounds__(256) void k_q(const float* __restrict__ X, const ushort_t* __restrict__ Wq,
                                           const float* __restrict__ bq, float* __restrict__ out){
  int m0 = (int)(blockIdx.x >> 3) * 128;
  int n0 = (int)(blockIdx.x & 7) * 128;
  __shared__ __align__(16) short As[128*32];
  __shared__ __align__(16) short Bs[128*32];
  int tid = threadIdx.x, lane = tid & 63, w = tid >> 6;
  int mW = (w & 1) * 64, nW = (w >> 1) * 64;
  int lm = lane & 15, lk = (lane >> 4) * 8;
  floatx4 acc[4][4];
#pragma unroll
  for(int i = 0; i < 4; i++)
#pragma unroll
    for(int j = 0; j < 4; j++) acc[i][j] = (floatx4)0.f;
  for(int ks = 0; ks < 32; ks++){
    int k0 = ks << 5;
    short8 va[2], vb[2];
#pragma unroll
    for(int i = 0; i < 2; i++){
      int f = i*256 + tid;
      int row = f >> 2, col = (f & 3) * 8;
      const float* p = X + (size_t)(m0+row)*D_ + (k0+col);
      float4 a = *(const float4*)p;
      float4 b2 = *(const float4*)(p + 4);
      short8 v;
      v[0]=(short)f2u(a.x); v[1]=(short)f2u(a.y); v[2]=(short)f2u(a.z); v[3]=(short)f2u(a.w);
      v[4]=(short)f2u(b2.x); v[5]=(short)f2u(b2.y); v[6]=(short)f2u(b2.z); v[7]=(short)f2u(b2.w);
      va[i] = v;
      vb[i] = *(const short8*)(Wq + (size_t)(n0+row)*D_ + (k0+col));
    }
    __syncthreads();
#pragma unroll
    for(int i = 0; i < 2; i++){
      int f = i*256 + tid;
      *(short8*)&As[f*8] = va[i];
      *(short8*)&Bs[f*8] = vb[i];
    }
    __syncthreads();
    short8 af[4], bfr[4];
#pragma unroll
    for(int i = 0; i < 4; i++) af[i]  = *(const short8*)&As[(mW + 16*i + lm)*32 + lk];
#pragma unroll
    for(int j = 0; j < 4; j++) bfr[j] = *(const short8*)&Bs[(nW + 16*j + lm)*32 + lk];
#pragma unroll
    for(int i = 0; i < 4; i++)
#pragma unroll
      for(int j = 0; j < 4; j++)
        acc[i][j] = __builtin_amdgcn_mfma_f32_16x16x32_bf16(af[i], bfr[j], acc[i][j], 0, 0, 0);
  }
#pragma unroll
  for(int j = 0; j < 4; j++){
    int col = n0 + nW + 16*j + lm;
    float bb = bq[col];
#pragma unroll
    for(int i = 0; i < 4; i++){
#pragma unroll
      for(int r = 0; r < 4; r++){
        int row = m0 + mW + 16*i + (lane>>4)*4 + r;
        out[(size_t)row*D_ + col] = acc[i][j][r] + bb;
      }
    }
  }
}

// ---------------- K7: attention; q read fp32 from d_out, ctx written fp32 to d_out ----------------
__global__ __launch_bounds__(256) void k_attn(float* __restrict__ out,
                                              const ushort_t* __restrict__ kten,
                                              const ushort_t* __restrict__ vTt){
  int x = blockIdx.x;
  int h = x & 15, b = (x >> 4) & 7, st = x >> 7;
  int s0 = st * 64;
  __shared__ __align__(16) short q_s[8*64*8];      // q: [kb<8][row<64][8]   (k-hat = dh)
  __shared__ __align__(16) short kp_s[8*256*8];    // k: [kb<8][row<256][8]; reused for P
  __shared__ __align__(16) short v_s[32*64*8];     // vT: [kb<32][row<64][8] (k-hat = key idx)
  int tid = threadIdx.x, lane = tid & 63, w = tid >> 6;
  int lm = lane & 15, lq = lane >> 4;
  const ushort_t* kb_g = kten + ((size_t)b*H_ + h)*K_*DH_;
  const ushort_t* vb_g = vTt + ((size_t)b*H_ + h)*DH_*K_;
  const float* qb_g = out + ((size_t)b*S_ + s0)*D_ + h*DH_;
  short8 vq[2], vk[8], vv[8];
#pragma unroll
  for(int i = 0; i < 2; i++){                       // q: 64x64 fp32 -> bf16
    int f = i*256 + tid;
    const float* p = qb_g + (size_t)(f & 63)*D_ + (f >> 6)*8;
    float4 a = *(const float4*)p;
    float4 b2 = *(const float4*)(p + 4);
    short8 v;
    v[0]=(short)f2u(a.x); v[1]=(short)f2u(a.y); v[2]=(short)f2u(a.z); v[3]=(short)f2u(a.w);
    v[4]=(short)f2u(b2.x); v[5]=(short)f2u(b2.y); v[6]=(short)f2u(b2.z); v[7]=(short)f2u(b2.w);
    vq[i] = v;
  }
#pragma unroll
  for(int i = 0; i < 8; i++){                       // k: 256x64
    int f = i*256 + tid;
    vk[i] = *(const short8*)(kb_g + (f & 255)*DH_ + (f >> 8)*8);
  }
#pragma unroll
  for(int i = 0; i < 8; i++){                       // vT: 64x256
    int f = i*256 + tid;
    vv[i] = *(const short8*)(vb_g + (f & 63)*K_ + (f >> 6)*8);
  }
#pragma unroll
  for(int i = 0; i < 2; i++) *(short8*)&q_s[(i*256 + tid)*8] = vq[i];
#pragma unroll
  for(int i = 0; i < 8; i++) *(short8*)&kp_s[(i*256 + tid)*8] = vk[i];
#pragma unroll
  for(int i = 0; i < 8; i++) *(short8*)&v_s[(i*256 + tid)*8] = vv[i];
  __syncthreads();

  int rw = w * 16;                                   // this wave's q rows
  floatx4 accS[16];
#pragma unroll
  for(int n = 0; n < 16; n++) accS[n] = (floatx4)0.f;
#pragma unroll
  for(int ks = 0; ks < 2; ks++){
    int kb = ks*4 + lq;
    short8 a = *(const short8*)&q_s[(kb*64 + rw + lm)*8];
#pragma unroll
    for(int n = 0; n < 16; n++){
      short8 bf_ = *(const short8*)&kp_s[(kb*256 + 16*n + lm)*8];
      accS[n] = __builtin_amdgcn_mfma_f32_16x16x32_bf16(a, bf_, accS[n], 0, 0, 0);
    }
  }
  const float scl = 0.125f;                          // 1/sqrt(64)
  float invr[4];
#pragma unroll
  for(int r = 0; r < 4; r++){
    float mx = -1e30f;
#pragma unroll
    for(int n = 0; n < 16; n++) mx = fmaxf(mx, accS[n][r]);
    mx = fmaxf(mx, __shfl_xor(mx, 1));
    mx = fmaxf(mx, __shfl_xor(mx, 2));
    mx = fmaxf(mx, __shfl_xor(mx, 4));
    mx = fmaxf(mx, __shfl_xor(mx, 8));
    float sum = 0.f;
#pragma unroll
    for(int n = 0; n < 16; n++){
      float p = __expf((accS[n][r] - mx) * scl);
      accS[n][r] = p;
      sum += p;
    }
    sum += __shfl_xor(sum, 1);
    sum += __shfl_xor(sum, 2);
    sum += __shfl_xor(sum, 4);
    sum += __shfl_xor(sum, 8);
    invr[r] = 1.f / sum;
  }
  __syncthreads();                                    // everyone done reading kp_s as K
  short* p_s = &kp_s[w * 4096];                       // per-wave P: [kb<32][row<16][8]
#pragma unroll
  for(int n = 0; n < 16; n++){
    int kb2 = 2*n + (lm >> 3);
    int e = lane & 7;
#pragma unroll
    for(int r = 0; r < 4; r++){
      int row = lq*4 + r;
      p_s[(kb2*16 + row)*8 + e] = (short)f2u(accS[n][r]);
    }
  }
  floatx4 accC[4];
#pragma unroll
  for(int n = 0; n < 4; n++) accC[n] = (floatx4)0.f;
#pragma unroll
  for(int ks = 0; ks < 8; ks++){
    int kb = ks*4 + lq;
    short8 a = *(const short8*)&p_s[(kb*16 + lm)*8];
#pragma unroll
    for(int n = 0; n < 4; n++){
      short8 bf_ = *(const short8*)&v_s[(kb*64 + 16*n + lm)*8];
      accC[n] = __builtin_amdgcn_mfma_f32_16x16x32_bf16(a, bf_, accC[n], 0, 0, 0);
    }
  }
#pragma unroll
  for(int n = 0; n < 4; n++){
#pragma unroll
    for(int r = 0; r < 4; r++){
      int srow = s0 + rw + lq*4 + r;
      out[((size_t)b*S_ + srow)*D_ + h*DH_ + 16*n + lm] = accC[n][r] * invr[r];
    }
  }
}

extern "C" void kernel_launch(void* const* d_in, const int* in_sizes, int n_in,
                              void* d_out, int out_size, void* d_ws, size_t ws_size,
                              hipStream_t stream) {
  (void)in_sizes; (void)n_in; (void)out_size; (void)ws_size;
  const float* X    = (const float*)d_in[0];
  const float* mask = (const float*)d_in[1];
  const float* Wq   = (const float*)d_in[2];
  const float* bq   = (const float*)d_in[3];
  const float* Wk   = (const float*)d_in[4];
  const float* bk   = (const float*)d_in[5];
  const float* Wv   = (const float*)d_in[6];
  const float* bv   = (const float*)d_in[7];
  const float* pk   = (const float*)d_in[8];
  const float* pv   = (const float*)d_in[9];
  float* out = (float*)d_out;

  char* wsp = (char*)d_ws;
  int*   len  = (int*)wsp;
  float* invl = (float*)(wsp + 64);
  float* spk  = (float*)(wsp + 256);
  float* spv  = (float*)(wsp + 256 + 8192);
  ushort_t* pkT  = (ushort_t*)(wsp + 32768);          // 256x4096 bf16, 2 MB
  ushort_t* pvT  = pkT  + (size_t)K_*S_;
  ushort_t* Wqb  = pvT  + (size_t)K_*S_;              // 1024x1024 bf16, 2 MB each
  ushort_t* Wkb  = Wqb  + (size_t)D_*D_;
  ushort_t* Wvb  = Wkb  + (size_t)D_*D_;
  ushort_t* XpK  = Wvb  + (size_t)D_*D_;              // 8x256x1024 bf16, 4 MB each
  ushort_t* XpV  = XpK  + (size_t)B_*K_*D_;
  ushort_t* kten = XpV  + (size_t)B_*K_*D_;
  ushort_t* vTt  = kten + (size_t)B_*K_*D_;
  // sp partials: 8*2*32*256 fp32 = 512 KB, in dead upper region of d_out
  // (XT uses first 67 MB; k_q overwrites d_out only after k_sp_red consumed these)
  float* part = (float*)((char*)d_out + 100u*1024*1024);

  hipLaunchKernelGGL(k_len, dim3(8), dim3(256), 0, stream, mask, len, invl);
  hipLaunchKernelGGL(k_sp_part, dim3(32,8,2), dim3(256), 0, stream, pk, pv, mask, part);
  hipLaunchKernelGGL(k_sp_red,  dim3(8,2), dim3(256), 0, stream, part, invl, spk, spv);
  hipLaunchKernelGGL(k_cvt, dim3(1024), dim3(256), 0, stream, Wq, Wqb, D_*D_/4);
  hipLaunchKernelGGL(k_cvt, dim3(1024), dim3(256), 0, stream, Wk, Wkb, D_*D_/4);
  hipLaunchKernelGGL(k_cvt, dim3(1024), dim3(256), 0, stream, Wv, Wvb, D_*D_/4);
  hipLaunchKernelGGL(k_trcvt, dim3(4,64,1), dim3(256), 0, stream, pk, pkT, S_, K_, 0L, 0L);
  hipLaunchKernelGGL(k_trcvt, dim3(4,64,1), dim3(256), 0, stream, pv, pvT, S_, K_, 0L, 0L);
  // X -> XT bf16 staged in d_out (dead until k_q overwrites it)
  hipLaunchKernelGGL(k_trcvt, dim3(16,64,8), dim3(256), 0, stream, X, (ushort_t*)out, S_, D_, (long)S_*D_, (long)D_*S_);
  hipLaunchKernelGGL(k_xp,  dim3(16,8,2), dim3(256), 0, stream, pkT, pvT, (const ushort_t*)out, len, invl, XpK, XpV);
  hipLaunchKernelGGL(k_kv,  dim3(16,8,2), dim3(256), 0, stream, XpK, XpV, Wkb, Wvb, bk, bv, spk, spv, kten, vTt);
  hipLaunchKernelGGL(k_q,   dim3(2048), dim3(256), 0, stream, X, Wqb, bq, out);
  hipLaunchKernelGGL(k_attn, dim3(8192), dim3(256), 0, stream, out, kten, vTt);
}

// Round 5
// 680.592 us; speedup vs baseline: 2.9336x; 1.0372x over previous
//
#include <hip/hip_runtime.h>
#include <stdint.h>

#define B_ 8
#define S_ 4096
#define D_ 1024
#define H_ 16
#define K_ 256
#define DH_ 64

typedef unsigned short ushort_t;
typedef __attribute__((ext_vector_type(8))) short short8;
typedef __attribute__((ext_vector_type(4))) short short4x;
typedef __attribute__((ext_vector_type(4))) float floatx4;

static __device__ __forceinline__ float u2f(unsigned short u){
  union { float f; unsigned int i; } v; v.i = ((unsigned int)u) << 16; return v.f;
}
static __device__ __forceinline__ unsigned short f2u(float f){
  union { float f; unsigned int i; } v; v.f = f;
  unsigned int r = v.i + 0x7fffu + ((v.i >> 16) & 1u);   // RNE bf16
  return (unsigned short)(r >> 16);
}

// ---------------- K1: per-batch lengths (mask fp32) ----------------
__global__ __launch_bounds__(256) void k_len(const float* __restrict__ mask,
                                             int* __restrict__ len, float* __restrict__ invl){
  int b = blockIdx.x, t = threadIdx.x;
  __shared__ int cnt[256];
  int c = 0;
  for(int s = t; s < S_; s += 256) c += (mask[b*S_ + s] > -1.0f) ? 1 : 0;
  cnt[t] = c; __syncthreads();
  for(int o = 128; o > 0; o >>= 1){ if(t < o) cnt[t] += cnt[t+o]; __syncthreads(); }
  if(t == 0){ len[b] = cnt[0]; invl[b] = rsqrtf((float)cnt[0]); }
}

// ---------------- K2a: partial masked column sums of proj over 128-row chunks ----------------
__global__ __launch_bounds__(256) void k_sp_part(const float* __restrict__ pk, const float* __restrict__ pv,
                                                 const float* __restrict__ mask, float* __restrict__ part){
  int c = blockIdx.x, b = blockIdx.y, sel = blockIdx.z;
  const float* p = sel ? pv : pk;
  int k = threadIdx.x;
  int s0 = c * 128;
  float acc = 0.f;
  for(int i = 0; i < 128; i++){
    int s = s0 + i;
    float mm = mask[b*S_ + s];
    if(mm > -1.0f) acc += p[(size_t)s*K_ + k];
  }
  part[(((size_t)(b*2 + sel))*32 + c)*K_ + k] = acc;
}

// ---------------- K2b: reduce partials, scale by invl ----------------
__global__ __launch_bounds__(256) void k_sp_red(const float* __restrict__ part, const float* __restrict__ invl,
                                                float* __restrict__ spk, float* __restrict__ spv){
  int b = blockIdx.x, sel = blockIdx.y, k = threadIdx.x;
  float acc = 0.f;
#pragma unroll
  for(int c = 0; c < 32; c++) acc += part[(((size_t)(b*2 + sel))*32 + c)*K_ + k];
  float r = acc * invl[b];
  if(sel) spv[b*K_ + k] = r; else spk[b*K_ + k] = r;
}

// ---------------- K2c: fp32 -> bf16 elementwise convert ----------------
__global__ __launch_bounds__(256) void k_cvt(const float* __restrict__ src, ushort_t* __restrict__ dst, int n4){
  int i = blockIdx.x * 256 + threadIdx.x;
  if(i >= n4) return;
  const float4 a = *(const float4*)(src + i*4);
  short4x v;
  v[0] = (short)f2u(a.x); v[1] = (short)f2u(a.y); v[2] = (short)f2u(a.z); v[3] = (short)f2u(a.w);
  *(short4x*)(dst + i*4) = v;
}

// ---------------- K3: 64x64-tile transpose fp32 -> bf16 ----------------
__global__ __launch_bounds__(256) void k_trcvt(const float* __restrict__ src, ushort_t* __restrict__ dst,
                                               int R, int C, long sstride, long dstride){
  __shared__ __align__(16) short t[64*66];
  const float* s0 = src + (size_t)blockIdx.z * sstride;
  ushort_t* d0 = dst + (size_t)blockIdx.z * dstride;
  int r0 = blockIdx.y * 64, c0 = blockIdx.x * 64;
  int tid = threadIdx.x;
#pragma unroll
  for(int i = 0; i < 2; i++){
    int f = tid + 256*i;
    int r = f >> 3, c = (f & 7) * 8;
    const float* p = s0 + (size_t)(r0 + r) * C + (c0 + c);
    float4 a = *(const float4*)p;
    float4 b2 = *(const float4*)(p + 4);
    short* q = &t[r*66 + c];
    q[0]=(short)f2u(a.x); q[1]=(short)f2u(a.y); q[2]=(short)f2u(a.z); q[3]=(short)f2u(a.w);
    q[4]=(short)f2u(b2.x); q[5]=(short)f2u(b2.y); q[6]=(short)f2u(b2.z); q[7]=(short)f2u(b2.w);
  }
  __syncthreads();
#pragma unroll
  for(int i = 0; i < 2; i++){
    int f = tid + 256*i;
    int dc = f >> 3, sg = f & 7;
    short8 v;
#pragma unroll
    for(int j = 0; j < 8; j++) v[j] = t[(sg*8 + j)*66 + dc];
    *(short8*)(d0 + (size_t)(c0 + dc) * R + (r0 + sg*8)) = v;
  }
}

// ---------------- K3b: transpose + straight copy, both bf16 (Tier 2) ----------------
__global__ __launch_bounds__(256) void k_trcvt_dual(const float* __restrict__ src, ushort_t* __restrict__ dstT,
                                                    ushort_t* __restrict__ dstS, int R, int C,
                                                    long sstride, long dTstride, long dSstride){
  __shared__ __align__(16) short t[64*66];
  const float* s0 = src + (size_t)blockIdx.z * sstride;
  ushort_t* dT = dstT + (size_t)blockIdx.z * dTstride;
  ushort_t* dS = dstS + (size_t)blockIdx.z * dSstride;
  int r0 = blockIdx.y * 64, c0 = blockIdx.x * 64;
  int tid = threadIdx.x;
#pragma unroll
  for(int i = 0; i < 2; i++){
    int f = tid + 256*i;
    int r = f >> 3, c = (f & 7) * 8;
    const float* p = s0 + (size_t)(r0 + r) * C + (c0 + c);
    float4 a = *(const float4*)p;
    float4 b2 = *(const float4*)(p + 4);
    short8 v;
    v[0]=(short)f2u(a.x); v[1]=(short)f2u(a.y); v[2]=(short)f2u(a.z); v[3]=(short)f2u(a.w);
    v[4]=(short)f2u(b2.x); v[5]=(short)f2u(b2.y); v[6]=(short)f2u(b2.z); v[7]=(short)f2u(b2.w);
    *(short8*)(dS + (size_t)(r0 + r) * C + (c0 + c)) = v;   // straight bf16 copy
    short* q = &t[r*66 + c];
    const int* v32 = (const int*)&v;
    int* q32 = (int*)q;
#pragma unroll
    for(int k2 = 0; k2 < 4; k2++) q32[k2] = v32[k2];
  }
  __syncthreads();
#pragma unroll
  for(int i = 0; i < 2; i++){
    int f = tid + 256*i;
    int dc = f >> 3, sg = f & 7;
    short8 v;
#pragma unroll
    for(int j = 0; j < 8; j++) v[j] = t[(sg*8 + j)*66 + dc];
    *(short8*)(dT + (size_t)(c0 + dc) * R + (r0 + sg*8)) = v;
  }
}

// ---------------- K4: Xp[b,m,d] = invl * sum_{s<L} pT[m,s]*XT[b,d,s]  (bf16 in, bf16 out) ----------------
__global__ __launch_bounds__(256) void k_xp(const ushort_t* __restrict__ pkT, const ushort_t* __restrict__ pvT,
      const ushort_t* __restrict__ XT, const int* __restrict__ len, const float* __restrict__ invl,
      ushort_t* __restrict__ XpK, ushort_t* __restrict__ XpV){
  int b = blockIdx.y, sel = blockIdx.z;
  const ushort_t* A = sel ? pvT : pkT;               // (256, 4096)
  ushort_t* hi = sel ? XpV : XpK;
  int m0 = (blockIdx.x & 1) * 128;
  int n0 = (blockIdx.x >> 1) * 128;
  const ushort_t* Bm = XT + (size_t)b * D_ * S_;     // (1024, 4096)
  int L = len[b];
  int nk = (L + 31) >> 5;
  bool tail = (L & 31) != 0;
  __shared__ __align__(16) short As[128*32];
  __shared__ __align__(16) short Bs[128*32];
  int tid = threadIdx.x, lane = tid & 63, w = tid >> 6;
  int mW = (w & 1) * 64, nW = (w >> 1) * 64;
  int lm = lane & 15, lk = (lane >> 4) * 8;
  floatx4 acc[4][4];
#pragma unroll
  for(int i = 0; i < 4; i++)
#pragma unroll
    for(int j = 0; j < 4; j++) acc[i][j] = (floatx4)0.f;
  for(int ks = 0; ks < nk; ks++){
    int k0 = ks << 5;
    short8 va[2], vb[2];
#pragma unroll
    for(int i = 0; i < 2; i++){
      int f = i*256 + tid;
      int row = f >> 2, col = (f & 3) * 8;
      va[i] = *(const short8*)(A  + (size_t)(m0+row)*S_ + (k0+col));
      vb[i] = *(const short8*)(Bm + (size_t)(n0+row)*S_ + (k0+col));
    }
    if(tail && ks == nk-1){
      int rlim = L - k0;
#pragma unroll
      for(int i = 0; i < 2; i++){
        int col = ((i*256 + tid) & 3) * 8;
#pragma unroll
        for(int j = 0; j < 8; j++) if(col + j >= rlim) va[i][j] = 0;
      }
    }
    __syncthreads();
#pragma unroll
    for(int i = 0; i < 2; i++){
      int f = i*256 + tid;
      *(short8*)&As[f*8] = va[i];
      *(short8*)&Bs[f*8] = vb[i];
    }
    __syncthreads();
    short8 af[4], bfr[4];
#pragma unroll
    for(int i = 0; i < 4; i++) af[i]  = *(const short8*)&As[(mW + 16*i + lm)*32 + lk];
#pragma unroll
    for(int j = 0; j < 4; j++) bfr[j] = *(const short8*)&Bs[(nW + 16*j + lm)*32 + lk];
#pragma unroll
    for(int i = 0; i < 4; i++)
#pragma unroll
      for(int j = 0; j < 4; j++)
        acc[i][j] = __builtin_amdgcn_mfma_f32_16x16x32_bf16(af[i], bfr[j], acc[i][j], 0, 0, 0);
  }
  float sc = invl[b];
#pragma unroll
  for(int i = 0; i < 4; i++){
#pragma unroll
    for(int j = 0; j < 4; j++){
      int col = n0 + nW + 16*j + lm;
#pragma unroll
      for(int r = 0; r < 4; r++){
        int row = m0 + mW + 16*i + (lane>>4)*4 + r;
        hi[((size_t)b*K_ + row)*D_ + col] = f2u(acc[i][j][r] * sc);
      }
    }
  }
}

// ---------------- K5: k/v = Xp @ W^T + sp*bias; k:(B,H,K,DH) bf16, v:(B,H,DH,K) bf16 ----------------
__global__ __launch_bounds__(256) void k_kv(const ushort_t* __restrict__ XpK, const ushort_t* __restrict__ XpV,
      const ushort_t* __restrict__ Wk, const ushort_t* __restrict__ Wv,
      const float* __restrict__ bk, const float* __restrict__ bv,
      const float* __restrict__ spk, const float* __restrict__ spv,
      ushort_t* __restrict__ kten, ushort_t* __restrict__ vTt){
  int b = blockIdx.y, sel = blockIdx.z;
  const ushort_t* Ab = (sel ? XpV : XpK) + (size_t)b*K_*D_;
  const ushort_t* W = sel ? Wv : Wk;
  const float* bias = sel ? bv : bk;
  const float* sp = (sel ? spv : spk) + b*K_;
  int m0 = (blockIdx.x & 1) * 128;
  int n0 = (blockIdx.x >> 1) * 128;
  __shared__ __align__(16) short As[128*32];
  __shared__ __align__(16) short Bs[128*32];
  int tid = threadIdx.x, lane = tid & 63, w = tid >> 6;
  int mW = (w & 1) * 64, nW = (w >> 1) * 64;
  int lm = lane & 15, lk = (lane >> 4) * 8;
  floatx4 acc[4][4];
#pragma unroll
  for(int i = 0; i < 4; i++)
#pragma unroll
    for(int j = 0; j < 4; j++) acc[i][j] = (floatx4)0.f;
  for(int ks = 0; ks < 32; ks++){
    int k0 = ks << 5;
    short8 va[2], vb[2];
#pragma unroll
    for(int i = 0; i < 2; i++){
      int f = i*256 + tid;
      int row = f >> 2, col = (f & 3) * 8;
      va[i] = *(const short8*)(Ab + (size_t)(m0+row)*D_ + (k0+col));
      vb[i] = *(const short8*)(W  + (size_t)(n0+row)*D_ + (k0+col));
    }
    __syncthreads();
#pragma unroll
    for(int i = 0; i < 2; i++){
      int f = i*256 + tid;
      *(short8*)&As[f*8] = va[i];
      *(short8*)&Bs[f*8] = vb[i];
    }
    __syncthreads();
    short8 af[4], bfr[4];
#pragma unroll
    for(int i = 0; i < 4; i++) af[i]  = *(const short8*)&As[(mW + 16*i + lm)*32 + lk];
#pragma unroll
    for(int j = 0; j < 4; j++) bfr[j] = *(const short8*)&Bs[(nW + 16*j + lm)*32 + lk];
#pragma unroll
    for(int i = 0; i < 4; i++)
#pragma unroll
      for(int j = 0; j < 4; j++)
        acc[i][j] = __builtin_amdgcn_mfma_f32_16x16x32_bf16(af[i], bfr[j], acc[i][j], 0, 0, 0);
  }
#pragma unroll
  for(int j = 0; j < 4; j++){
    int col = n0 + nW + 16*j + lm;
    float bb = bias[col];
    int hcol = col >> 6, dcol = col & 63;
#pragma unroll
    for(int i = 0; i < 4; i++){
#pragma unroll
      for(int r = 0; r < 4; r++){
        int row = m0 + mW + 16*i + (lane>>4)*4 + r;
        float val = acc[i][j][r] + sp[row]*bb;
        if(sel == 0) kten[(((size_t)b*H_ + hcol)*K_ + row)*DH_ + dcol] = f2u(val);
        else         vTt [(((size_t)b*H_ + hcol)*DH_ + dcol)*K_ + row] = f2u(val);
      }
    }
  }
}

// ---------------- K6: q = X @ Wq^T + bq  -> d_out (B,S,D) fp32  (Tier 0) ----------------
__global__ __launch_bounds__(256) void k_q(const float* __restrict__ X, const ushort_t* __restrict__ Wq,
                                           const float* __restrict__ bq, float* __restrict__ out){
  int m0 = (int)(blockIdx.x >> 3) * 128;
  int n0 = (int)(blockIdx.x & 7) * 128;
  __shared__ __align__(16) short As[128*32];
  __shared__ __align__(16) short Bs[128*32];
  int tid = threadIdx.x, lane = tid & 63, w = tid >> 6;
  int mW = (w & 1) * 64, nW = (w >> 1) * 64;
  int lm = lane & 15, lk = (lane >> 4) * 8;
  floatx4 acc[4][4];
#pragma unroll
  for(int i = 0; i < 4; i++)
#pragma unroll
    for(int j = 0; j < 4; j++) acc[i][j] = (floatx4)0.f;
  for(int ks = 0; ks < 32; ks++){
    int k0 = ks << 5;
    short8 va[2], vb[2];
#pragma unroll
    for(int i = 0; i < 2; i++){
      int f = i*256 + tid;
      int row = f >> 2, col = (f & 3) * 8;
      const float* p = X + (size_t)(m0+row)*D_ + (k0+col);
      float4 a = *(const float4*)p;
      float4 b2 = *(const float4*)(p + 4);
      short8 v;
      v[0]=(short)f2u(a.x); v[1]=(short)f2u(a.y); v[2]=(short)f2u(a.z); v[3]=(short)f2u(a.w);
      v[4]=(short)f2u(b2.x); v[5]=(short)f2u(b2.y); v[6]=(short)f2u(b2.z); v[7]=(short)f2u(b2.w);
      va[i] = v;
      vb[i] = *(const short8*)(Wq + (size_t)(n0+row)*D_ + (k0+col));
    }
    __syncthreads();
#pragma unroll
    for(int i = 0; i < 2; i++){
      int f = i*256 + tid;
      *(short8*)&As[f*8] = va[i];
      *(short8*)&Bs[f*8] = vb[i];
    }
    __syncthreads();
    short8 af[4], bfr[4];
#pragma unroll
    for(int i = 0; i < 4; i++) af[i]  = *(const short8*)&As[(mW + 16*i + lm)*32 + lk];
#pragma unroll
    for(int j = 0; j < 4; j++) bfr[j] = *(const short8*)&Bs[(nW + 16*j + lm)*32 + lk];
#pragma unroll
    for(int i = 0; i < 4; i++)
#pragma unroll
      for(int j = 0; j < 4; j++)
        acc[i][j] = __builtin_amdgcn_mfma_f32_16x16x32_bf16(af[i], bfr[j], acc[i][j], 0, 0, 0);
  }
#pragma unroll
  for(int j = 0; j < 4; j++){
    int col = n0 + nW + 16*j + lm;
    float bb = bq[col];
#pragma unroll
    for(int i = 0; i < 4; i++){
#pragma unroll
      for(int r = 0; r < 4; r++){
        int row = m0 + mW + 16*i + (lane>>4)*4 + r;
        out[(size_t)row*D_ + col] = acc[i][j][r] + bb;
      }
    }
  }
}

// ---------------- K6b: q = Xb @ Wq^T + bq, all bf16, q -> ws bf16 (Tier 2) ----------------
__global__ __launch_bounds__(256) void k_q2(const ushort_t* __restrict__ Xb, const ushort_t* __restrict__ Wq,
                                            const float* __restrict__ bq, ushort_t* __restrict__ qb){
  int m0 = (int)(blockIdx.x >> 3) * 128;
  int n0 = (int)(blockIdx.x & 7) * 128;
  __shared__ __align__(16) short As[128*32];
  __shared__ __align__(16) short Bs[128*32];
  int tid = threadIdx.x, lane = tid & 63, w = tid >> 6;
  int mW = (w & 1) * 64, nW = (w >> 1) * 64;
  int lm = lane & 15, lk = (lane >> 4) * 8;
  floatx4 acc[4][4];
#pragma unroll
  for(int i = 0; i < 4; i++)
#pragma unroll
    for(int j = 0; j < 4; j++) acc[i][j] = (floatx4)0.f;
  for(int ks = 0; ks < 32; ks++){
    int k0 = ks << 5;
    short8 va[2], vb[2];
#pragma unroll
    for(int i = 0; i < 2; i++){
      int f = i*256 + tid;
      int row = f >> 2, col = (f & 3) * 8;
      va[i] = *(const short8*)(Xb + (size_t)(m0+row)*D_ + (k0+col));
      vb[i] = *(const short8*)(Wq + (size_t)(n0+row)*D_ + (k0+col));
    }
    __syncthreads();
#pragma unroll
    for(int i = 0; i < 2; i++){
      int f = i*256 + tid;
      *(short8*)&As[f*8] = va[i];
      *(short8*)&Bs[f*8] = vb[i];
    }
    __syncthreads();
    short8 af[4], bfr[4];
#pragma unroll
    for(int i = 0; i < 4; i++) af[i]  = *(const short8*)&As[(mW + 16*i + lm)*32 + lk];
#pragma unroll
    for(int j = 0; j < 4; j++) bfr[j] = *(const short8*)&Bs[(nW + 16*j + lm)*32 + lk];
#pragma unroll
    for(int i = 0; i < 4; i++)
#pragma unroll
      for(int j = 0; j < 4; j++)
        acc[i][j] = __builtin_amdgcn_mfma_f32_16x16x32_bf16(af[i], bfr[j], acc[i][j], 0, 0, 0);
  }
#pragma unroll
  for(int j = 0; j < 4; j++){
    int col = n0 + nW + 16*j + lm;
    float bb = bq[col];
#pragma unroll
    for(int i = 0; i < 4; i++){
#pragma unroll
      for(int r = 0; r < 4; r++){
        int row = m0 + mW + 16*i + (lane>>4)*4 + r;
        qb[(size_t)row*D_ + col] = f2u(acc[i][j][r] + bb);
      }
    }
  }
}

// ---------------- K7: attention, q fp32 from d_out (Tier 0) ----------------
__global__ __launch_bounds__(256) void k_attn(float* __restrict__ out,
                                              const ushort_t* __restrict__ kten,
                                              const ushort_t* __restrict__ vTt){
  int x = blockIdx.x;
  int h = x & 15, b = (x >> 4) & 7, st = x >> 7;
  int s0 = st * 64;
  __shared__ __align__(16) short q_s[8*64*8];
  __shared__ __align__(16) short kp_s[8*256*8];
  __shared__ __align__(16) short v_s[32*64*8];
  int tid = threadIdx.x, lane = tid & 63, w = tid >> 6;
  int lm = lane & 15, lq = lane >> 4;
  const ushort_t* kb_g = kten + ((size_t)b*H_ + h)*K_*DH_;
  const ushort_t* vb_g = vTt + ((size_t)b*H_ + h)*DH_*K_;
  const float* qb_g = out + ((size_t)b*S_ + s0)*D_ + h*DH_;
  short8 vq[2], vk[8], vv[8];
#pragma unroll
  for(int i = 0; i < 2; i++){
    int f = i*256 + tid;
    const float* p = qb_g + (size_t)(f & 63)*D_ + (f >> 6)*8;
    float4 a = *(const float4*)p;
    float4 b2 = *(const float4*)(p + 4);
    short8 v;
    v[0]=(short)f2u(a.x); v[1]=(short)f2u(a.y); v[2]=(short)f2u(a.z); v[3]=(short)f2u(a.w);
    v[4]=(short)f2u(b2.x); v[5]=(short)f2u(b2.y); v[6]=(short)f2u(b2.z); v[7]=(short)f2u(b2.w);
    vq[i] = v;
  }
#pragma unroll
  for(int i = 0; i < 8; i++){
    int f = i*256 + tid;
    vk[i] = *(const short8*)(kb_g + (f & 255)*DH_ + (f >> 8)*8);
  }
#pragma unroll
  for(int i = 0; i < 8; i++){
    int f = i*256 + tid;
    vv[i] = *(const short8*)(vb_g + (f & 63)*K_ + (f >> 6)*8);
  }
#pragma unroll
  for(int i = 0; i < 2; i++) *(short8*)&q_s[(i*256 + tid)*8] = vq[i];
#pragma unroll
  for(int i = 0; i < 8; i++) *(short8*)&kp_s[(i*256 + tid)*8] = vk[i];
#pragma unroll
  for(int i = 0; i < 8; i++) *(short8*)&v_s[(i*256 + tid)*8] = vv[i];
  __syncthreads();

  int rw = w * 16;
  floatx4 accS[16];
#pragma unroll
  for(int n = 0; n < 16; n++) accS[n] = (floatx4)0.f;
#pragma unroll
  for(int ks = 0; ks < 2; ks++){
    int kb = ks*4 + lq;
    short8 a = *(const short8*)&q_s[(kb*64 + rw + lm)*8];
#pragma unroll
    for(int n = 0; n < 16; n++){
      short8 bf_ = *(const short8*)&kp_s[(kb*256 + 16*n + lm)*8];
      accS[n] = __builtin_amdgcn_mfma_f32_16x16x32_bf16(a, bf_, accS[n], 0, 0, 0);
    }
  }
  const float scl = 0.125f;
  float invr[4];
#pragma unroll
  for(int r = 0; r < 4; r++){
    float mx = -1e30f;
#pragma unroll
    for(int n = 0; n < 16; n++) mx = fmaxf(mx, accS[n][r]);
    mx = fmaxf(mx, __shfl_xor(mx, 1));
    mx = fmaxf(mx, __shfl_xor(mx, 2));
    mx = fmaxf(mx, __shfl_xor(mx, 4));
    mx = fmaxf(mx, __shfl_xor(mx, 8));
    float sum = 0.f;
#pragma unroll
    for(int n = 0; n < 16; n++){
      float p = __expf((accS[n][r] - mx) * scl);
      accS[n][r] = p;
      sum += p;
    }
    sum += __shfl_xor(sum, 1);
    sum += __shfl_xor(sum, 2);
    sum += __shfl_xor(sum, 4);
    sum += __shfl_xor(sum, 8);
    invr[r] = 1.f / sum;
  }
  __syncthreads();
  short* p_s = &kp_s[w * 4096];
#pragma unroll
  for(int n = 0; n < 16; n++){
    int kb2 = 2*n + (lm >> 3);
    int e = lane & 7;
#pragma unroll
    for(int r = 0; r < 4; r++){
      int row = lq*4 + r;
      p_s[(kb2*16 + row)*8 + e] = (short)f2u(accS[n][r]);
    }
  }
  floatx4 accC[4];
#pragma unroll
  for(int n = 0; n < 4; n++) accC[n] = (floatx4)0.f;
#pragma unroll
  for(int ks = 0; ks < 8; ks++){
    int kb = ks*4 + lq;
    short8 a = *(const short8*)&p_s[(kb*16 + lm)*8];
#pragma unroll
    for(int n = 0; n < 4; n++){
      short8 bf_ = *(const short8*)&v_s[(kb*64 + 16*n + lm)*8];
      accC[n] = __builtin_amdgcn_mfma_f32_16x16x32_bf16(a, bf_, accC[n], 0, 0, 0);
    }
  }
#pragma unroll
  for(int n = 0; n < 4; n++){
#pragma unroll
    for(int r = 0; r < 4; r++){
      int srow = s0 + rw + lq*4 + r;
      out[((size_t)b*S_ + srow)*D_ + h*DH_ + 16*n + lm] = accC[n][r] * invr[r];
    }
  }
}

// ---------------- K7b: attention, q bf16 from ws (Tier 2) ----------------
__global__ __launch_bounds__(256) void k_attn2(float* __restrict__ out, const ushort_t* __restrict__ qb,
                                               const ushort_t* __restrict__ kten,
                                               const ushort_t* __restrict__ vTt){
  int x = blockIdx.x;
  int h = x & 15, b = (x >> 4) & 7, st = x >> 7;
  int s0 = st * 64;
  __shared__ __align__(16) short q_s[8*64*8];
  __shared__ __align__(16) short kp_s[8*256*8];
  __shared__ __align__(16) short v_s[32*64*8];
  int tid = threadIdx.x, lane = tid & 63, w = tid >> 6;
  int lm = lane & 15, lq = lane >> 4;
  const ushort_t* kb_g = kten + ((size_t)b*H_ + h)*K_*DH_;
  const ushort_t* vb_g = vTt + ((size_t)b*H_ + h)*DH_*K_;
  const ushort_t* qg = qb + ((size_t)b*S_ + s0)*D_ + h*DH_;
  short8 vq[2], vk[8], vv[8];
#pragma unroll
  for(int i = 0; i < 2; i++){
    int f = i*256 + tid;
    vq[i] = *(const short8*)(qg + (size_t)(f & 63)*D_ + (f >> 6)*8);
  }
#pragma unroll
  for(int i = 0; i < 8; i++){
    int f = i*256 + tid;
    vk[i] = *(const short8*)(kb_g + (f & 255)*DH_ + (f >> 8)*8);
  }
#pragma unroll
  for(int i = 0; i < 8; i++){
    int f = i*256 + tid;
    vv[i] = *(const short8*)(vb_g + (f & 63)*K_ + (f >> 6)*8);
  }
#pragma unroll
  for(int i = 0; i < 2; i++) *(short8*)&q_s[(i*256 + tid)*8] = vq[i];
#pragma unroll
  for(int i = 0; i < 8; i++) *(short8*)&kp_s[(i*256 + tid)*8] = vk[i];
#pragma unroll
  for(int i = 0; i < 8; i++) *(short8*)&v_s[(i*256 + tid)*8] = vv[i];
  __syncthreads();

  int rw = w * 16;
  floatx4 accS[16];
#pragma unroll
  for(int n = 0; n < 16; n++) accS[n] = (floatx4)0.f;
#pragma unroll
  for(int ks = 0; ks < 2; ks++){
    int kb = ks*4 + lq;
    short8 a = *(const short8*)&q_s[(kb*64 + rw + lm)*8];
#pragma unroll
    for(int n = 0; n < 16; n++){
      short8 bf_ = *(const short8*)&kp_s[(kb*256 + 16*n + lm)*8];
      accS[n] = __builtin_amdgcn_mfma_f32_16x16x32_bf16(a, bf_, accS[n], 0, 0, 0);
    }
  }
  const float scl = 0.125f;
  float invr[4];
#pragma unroll
  for(int r = 0; r < 4; r++){
    float mx = -1e30f;
#pragma unroll
    for(int n = 0; n < 16; n++) mx = fmaxf(mx, accS[n][r]);
    mx = fmaxf(mx, __shfl_xor(mx, 1));
    mx = fmaxf(mx, __shfl_xor(mx, 2));
    mx = fmaxf(mx, __shfl_xor(mx, 4));
    mx = fmaxf(mx, __shfl_xor(mx, 8));
    float sum = 0.f;
#pragma unroll
    for(int n = 0; n < 16; n++){
      float p = __expf((accS[n][r] - mx) * scl);
      accS[n][r] = p;
      sum += p;
    }
    sum += __shfl_xor(sum, 1);
    sum += __shfl_xor(sum, 2);
    sum += __shfl_xor(sum, 4);
    sum += __shfl_xor(sum, 8);
    invr[r] = 1.f / sum;
  }
  __syncthreads();
  short* p_s = &kp_s[w * 4096];
#pragma unroll
  for(int n = 0; n < 16; n++){
    int kb2 = 2*n + (lm >> 3);
    int e = lane & 7;
#pragma unroll
    for(int r = 0; r < 4; r++){
      int row = lq*4 + r;
      p_s[(kb2*16 + row)*8 + e] = (short)f2u(accS[n][r]);
    }
  }
  floatx4 accC[4];
#pragma unroll
  for(int n = 0; n < 4; n++) accC[n] = (floatx4)0.f;
#pragma unroll
  for(int ks = 0; ks < 8; ks++){
    int kb = ks*4 + lq;
    short8 a = *(const short8*)&p_s[(kb*16 + lm)*8];
#pragma unroll
    for(int n = 0; n < 4; n++){
      short8 bf_ = *(const short8*)&v_s[(kb*64 + 16*n + lm)*8];
      accC[n] = __builtin_amdgcn_mfma_f32_16x16x32_bf16(a, bf_, accC[n], 0, 0, 0);
    }
  }
#pragma unroll
  for(int n = 0; n < 4; n++){
#pragma unroll
    for(int r = 0; r < 4; r++){
      int srow = s0 + rw + lq*4 + r;
      out[((size_t)b*S_ + srow)*D_ + h*DH_ + 16*n + lm] = accC[n][r] * invr[r];
    }
  }
}

extern "C" void kernel_launch(void* const* d_in, const int* in_sizes, int n_in,
                              void* d_out, int out_size, void* d_ws, size_t ws_size,
                              hipStream_t stream) {
  (void)in_sizes; (void)n_in; (void)out_size;
  const float* X    = (const float*)d_in[0];
  const float* mask = (const float*)d_in[1];
  const float* Wq   = (const float*)d_in[2];
  const float* bq   = (const float*)d_in[3];
  const float* Wk   = (const float*)d_in[4];
  const float* bk   = (const float*)d_in[5];
  const float* Wv   = (const float*)d_in[6];
  const float* bv   = (const float*)d_in[7];
  const float* pk   = (const float*)d_in[8];
  const float* pv   = (const float*)d_in[9];
  float* out = (float*)d_out;

  char* wsp = (char*)d_ws;
  int*   len  = (int*)wsp;
  float* invl = (float*)(wsp + 64);
  float* spk  = (float*)(wsp + 256);
  float* spv  = (float*)(wsp + 256 + 8192);
  ushort_t* pkT  = (ushort_t*)(wsp + 32768);          // 256x4096 bf16, 2 MB
  ushort_t* pvT  = pkT  + (size_t)K_*S_;
  ushort_t* Wqb  = pvT  + (size_t)K_*S_;              // 1024x1024 bf16, 2 MB each
  ushort_t* Wkb  = Wqb  + (size_t)D_*D_;
  ushort_t* Wvb  = Wkb  + (size_t)D_*D_;
  ushort_t* XpK  = Wvb  + (size_t)D_*D_;              // 8x256x1024 bf16, 4 MB each
  ushort_t* XpV  = XpK  + (size_t)B_*K_*D_;
  ushort_t* kten = XpV  + (size_t)B_*K_*D_;
  ushort_t* vTt  = kten + (size_t)B_*K_*D_;
  ushort_t* Xb   = vTt  + (size_t)B_*K_*D_;           // Tier 2: 8x4096x1024 bf16, 64 MB
  ushort_t* qb   = Xb   + (size_t)B_*S_*D_;           // Tier 2: 64 MB
  size_t tier2_need = (size_t)((char*)(qb + (size_t)B_*S_*D_) - wsp);
  int tier2 = ws_size >= tier2_need;
  // sp partials: 512 KB at d_out+100MB (dead region until k_q/k_attn writes)
  float* part = (float*)((char*)d_out + 100u*1024*1024);

  hipLaunchKernelGGL(k_len, dim3(8), dim3(256), 0, stream, mask, len, invl);
  hipLaunchKernelGGL(k_sp_part, dim3(32,8,2), dim3(256), 0, stream, pk, pv, mask, part);
  hipLaunchKernelGGL(k_sp_red,  dim3(8,2), dim3(256), 0, stream, part, invl, spk, spv);
  hipLaunchKernelGGL(k_cvt, dim3(1024), dim3(256), 0, stream, Wq, Wqb, D_*D_/4);
  hipLaunchKernelGGL(k_cvt, dim3(1024), dim3(256), 0, stream, Wk, Wkb, D_*D_/4);
  hipLaunchKernelGGL(k_cvt, dim3(1024), dim3(256), 0, stream, Wv, Wvb, D_*D_/4);
  hipLaunchKernelGGL(k_trcvt, dim3(4,64,1), dim3(256), 0, stream, pk, pkT, S_, K_, 0L, 0L);
  hipLaunchKernelGGL(k_trcvt, dim3(4,64,1), dim3(256), 0, stream, pv, pvT, S_, K_, 0L, 0L);
  if(tier2){
    // XT -> d_out (dead until k_attn2 writes ctx), Xb -> ws
    hipLaunchKernelGGL(k_trcvt_dual, dim3(16,64,8), dim3(256), 0, stream, X, (ushort_t*)out, Xb,
                       S_, D_, (long)S_*D_, (long)D_*S_, (long)S_*D_);
    hipLaunchKernelGGL(k_xp,  dim3(16,8,2), dim3(256), 0, stream, pkT, pvT, (const ushort_t*)out, len, invl, XpK, XpV);
    hipLaunchKernelGGL(k_kv,  dim3(16,8,2), dim3(256), 0, stream, XpK, XpV, Wkb, Wvb, bk, bv, spk, spv, kten, vTt);
    hipLaunchKernelGGL(k_q2,  dim3(2048), dim3(256), 0, stream, Xb, Wqb, bq, qb);
    hipLaunchKernelGGL(k_attn2, dim3(8192), dim3(256), 0, stream, out, qb, kten, vTt);
  } else {
    hipLaunchKernelGGL(k_trcvt, dim3(16,64,8), dim3(256), 0, stream, X, (ushort_t*)out, S_, D_, (long)S_*D_, (long)D_*S_);
    hipLaunchKernelGGL(k_xp,  dim3(16,8,2), dim3(256), 0, stream, pkT, pvT, (const ushort_t*)out, len, invl, XpK, XpV);
    hipLaunchKernelGGL(k_kv,  dim3(16,8,2), dim3(256), 0, stream, XpK, XpV, Wkb, Wvb, bk, bv, spk, spv, kten, vTt);
    hipLaunchKernelGGL(k_q,   dim3(2048), dim3(256), 0, stream, X, Wqb, bq, out);
    hipLaunchKernelGGL(k_attn, dim3(8192), dim3(256), 0, stream, out, kten, vTt);
  }
}